// Round 3
// baseline (385.229 us; speedup 1.0000x reference)
//
#include <hip/hip_runtime.h>
#include <math.h>

#define NG 4096
#define NN 262144
#define D 128
#define M1 64
#define NH 8
#define GPB 4          // graphs per block (contiguous node range, batch sorted)
#define EPS 1e-6f

typedef __attribute__((ext_vector_type(8))) short short8;
typedef __attribute__((ext_vector_type(8))) unsigned char uchar8;
typedef __attribute__((ext_vector_type(4))) float f32x4;

__device__ inline float leaky(float x) { return x > 0.f ? x : 0.01f * x; }

// fp32 -> bf16 round-to-nearest-even
__device__ inline short f2bf(float f) {
  union { float f; unsigned u; } v; v.f = f;
  unsigned r = (v.u + 0x7fffu + ((v.u >> 16) & 1u)) >> 16;
  return (short)r;
}
__device__ inline float bf2f(short s) {
  union { unsigned u; float f; } v;
  v.u = ((unsigned)(unsigned short)s) << 16;
  return v.f;
}

// ---------------------------------------------------------------------------
// Prep: blocks 0..35 transpose W3 -> W3T[128,1024] bf16, W4 -> W4T[128,128];
// blocks 36..51: starts[g] = lower_bound(batch, g); starts[NG] = NN.
// ---------------------------------------------------------------------------
__global__ __launch_bounds__(256) void k0b_prep(
    const float* __restrict__ W3, const float* __restrict__ W4,
    const int* __restrict__ batch,
    short* __restrict__ W3T, short* __restrict__ W4T,
    int* __restrict__ starts) {
  __shared__ float tile[64][65];
  int b = blockIdx.x, t = threadIdx.x;
  if (b >= 36) {
    int g = (b - 36) * 256 + t;
    int lo = 0, hi = NN;
    while (lo < hi) {
      int mid = (lo + hi) >> 1;
      if (batch[mid] < g) lo = mid + 1; else hi = mid;
    }
    starts[g] = lo;
    if (g == 0) starts[NG] = NN;
    return;
  }
  const float* src; short* dst; int kt, nt, tkl;
  if (b < 32) { src = W3; dst = W3T; kt = b >> 1; nt = b & 1; tkl = 1024; }
  else        { src = W4; dst = W4T; kt = (b - 32) >> 1; nt = (b - 32) & 1; tkl = 128; }

#pragma unroll
  for (int i = 0; i < 4; ++i) {
    int id = t + 256 * i;
    int r = id >> 4, c4 = (id & 15) * 4;
    float4 v = *(const float4*)(src + (size_t)(kt * 64 + r) * D + nt * 64 + c4);
    tile[r][c4 + 0] = v.x; tile[r][c4 + 1] = v.y;
    tile[r][c4 + 2] = v.z; tile[r][c4 + 3] = v.w;
  }
  __syncthreads();
  int n = t >> 2, kb = (t & 3) * 16;
  short8 p0, p1;
#pragma unroll
  for (int j = 0; j < 8; ++j) {
    p0[j] = f2bf(tile[kb + j][n]);
    p1[j] = f2bf(tile[kb + 8 + j][n]);
  }
  short* o = dst + (size_t)(nt * 64 + n) * tkl + kt * 64 + kb;
  *(short8*)o = p0;
  *(short8*)(o + 8) = p1;
}

// ---------------------------------------------------------------------------
// FUSED: one block owns graphs [G0, G0+4) = contiguous nodes [s0, s1).
// Aggregation accumulates in REGISTERS (fixed 4-graph window); 3 barriers per
// 128-node chunk; LDS 40.7 KB -> 4 blocks/CU.
// Round-3: reverted round-2 micro-opts (packed/permuted LN store, removed
// LN->GEMM2 barrier, __expf) to round-1-verified forms; kept macro structure.
// ---------------------------------------------------------------------------
__global__ __launch_bounds__(256, 4) void k_fused(
    const float* __restrict__ feat, const int* __restrict__ batch,
    const int* __restrict__ starts,
    const float* __restrict__ W1, const float* __restrict__ b1,
    const float* __restrict__ g1, const float* __restrict__ beta1,
    const float* __restrict__ W2, const float* __restrict__ b2,
    const short* __restrict__ W3T, const float* __restrict__ b3,
    const float* __restrict__ g3, const float* __restrict__ beta3,
    const short* __restrict__ W4T, const float* __restrict__ b4,
    const float* __restrict__ g4, const float* __restrict__ beta4,
    float* __restrict__ out) {
  // prologue weights union epilogue buffers (disjoint in time)
  __shared__ __align__(16) union SOvl {
    struct { short W1T[M1][D + 8]; short W2T[16][M1 + 8]; } p;  // 19712 B
    struct { short hbuf2[16][136]; float red[4][2][16]; } e;    //  4864 B
  } ovl;
  __shared__ __align__(16) short hb[128][72];        // 18432 B; epilogue: aL
  __shared__ __align__(16) short attB[NH][136];      //  2176 B
  __shared__ float sL[GPB][NH];                      //   128 B
  __shared__ unsigned char giL2[2][128];             //   256 B   total 40704 B

  short (*aL)[1040] = (short(*)[1040])&hb[0][0];     // [gi][h*128+d] bf16

  int t = threadIdx.x;
  int G0 = blockIdx.x * GPB;
  int w = t >> 6, l = t & 63;
  int lr = l & 15, lq = l >> 4;
  int dA = w * 32 + lr, dB = dA + 16;

  // ---- one-time staging: W1T transposed bf16; W2T (unpermuted, round-1 form)
#pragma unroll
  for (int i = 0; i < 8; ++i) {
    int idx4 = t + 256 * i;
    int k = idx4 >> 4, j = (idx4 & 15) * 4;
    float4 wv = *(const float4*)(W1 + k * M1 + j);
    ovl.p.W1T[j + 0][k] = f2bf(wv.x);
    ovl.p.W1T[j + 1][k] = f2bf(wv.y);
    ovl.p.W1T[j + 2][k] = f2bf(wv.z);
    ovl.p.W1T[j + 3][k] = f2bf(wv.w);
  }
#pragma unroll
  for (int i = 0; i < 4; ++i) {
    int e = t * 4 + i;
    int hh = e >> 6, j = e & 63;
    ovl.p.W2T[hh][j] = (hh < NH) ? f2bf(W2[j * NH + hh]) : (short)0;
  }
  if (t < GPB * NH) (&sL[0][0])[t] = 0.f;

  // per-lane constants hoisted
  float b1v[4], g1v[4], btv[4];
#pragma unroll
  for (int nt = 0; nt < 4; ++nt) {
    b1v[nt] = b1[nt * 16 + lr];
    g1v[nt] = g1[nt * 16 + lr];
    btv[nt] = beta1[nt * 16 + lr];
  }
  float b2v = b2[lr & 7];

  // register aggregation accumulators: fixed window covers graphs 0..3.
  // C row m=lq*4+r -> (gi = m>>3 (+2 for c1x), h = m&7); col -> d.
  f32x4 c00 = (f32x4){0.f, 0.f, 0.f, 0.f};
  f32x4 c01 = (f32x4){0.f, 0.f, 0.f, 0.f};
  f32x4 c10 = (f32x4){0.f, 0.f, 0.f, 0.f};
  f32x4 c11 = (f32x4){0.f, 0.f, 0.f, 0.f};

  int s0 = starts[G0], s1 = starts[G0 + GPB];
  int nchunks = (s1 - s0 + 127) >> 7;

  for (int c = 0; c < nchunks; ++c) {
    int base = s0 + (c << 7);
    int nvalid = min(128, s1 - base);
    unsigned char* gi = giL2[c & 1];
    if (t < 128)
      gi[t] = (t < nvalid) ? (unsigned char)(batch[base + t] - G0)
                           : (unsigned char)255;  // tail sentinel

    // ---- A-frags (GEMM1) + B-frags (aggregation) issued together; latency
    // overlaps other blocks' compute (4 blocks/CU).
    short8 afr[2][4];
#pragma unroll
    for (int mt = 0; mt < 2; ++mt) {
      int node = base + w * 32 + mt * 16 + lr;
      node = node < NN ? node : NN - 1;   // tail clamp (masked later)
      const float* rp = feat + (size_t)node * D + lq * 8;
#pragma unroll
      for (int cc = 0; cc < 4; ++cc) {
        float4 x0 = *(const float4*)(rp + cc * 32);
        float4 x1 = *(const float4*)(rp + cc * 32 + 4);
        short8 a;
        a[0] = f2bf(x0.x); a[1] = f2bf(x0.y); a[2] = f2bf(x0.z); a[3] = f2bf(x0.w);
        a[4] = f2bf(x1.x); a[5] = f2bf(x1.y); a[6] = f2bf(x1.z); a[7] = f2bf(x1.w);
        afr[mt][cc] = a;
      }
    }
    short8 bfA[4], bfB[4];
#pragma unroll
    for (int kc = 0; kc < 4; ++kc) {
      short8 ba, bb;
#pragma unroll
      for (int j = 0; j < 8; ++j) {
        int node = base + kc * 32 + lq * 8 + j;
        node = node < NN ? node : NN - 1;
        const float* fp = feat + (size_t)node * D;
        ba[j] = f2bf(fp[dA]);
        bb[j] = f2bf(fp[dB]);
      }
      bfA[kc] = ba;
      bfB[kc] = bb;
    }
    __syncthreads();  // BAR1: gi visible; prev chunk's attB/gi reads done

    // ---- GEMM1: [32 nodes x 64 j], K=128
    f32x4 acc[2][4];
#pragma unroll
    for (int mt = 0; mt < 2; ++mt)
#pragma unroll
      for (int nt = 0; nt < 4; ++nt) acc[mt][nt] = (f32x4){0.f, 0.f, 0.f, 0.f};
    __builtin_amdgcn_s_setprio(1);
#pragma unroll
    for (int cc = 0; cc < 4; ++cc) {
#pragma unroll
      for (int nt = 0; nt < 4; ++nt) {
        short8 bfr = *(const short8*)&ovl.p.W1T[nt * 16 + lr][cc * 32 + lq * 8];
        acc[0][nt] = __builtin_amdgcn_mfma_f32_16x16x32_bf16(afr[0][cc], bfr, acc[0][nt], 0, 0, 0);
        acc[1][nt] = __builtin_amdgcn_mfma_f32_16x16x32_bf16(afr[1][cc], bfr, acc[1][nt], 0, 0, 0);
      }
    }
    __builtin_amdgcn_s_setprio(0);

    // ---- bias + leaky + LN over j(64); h -> hb bf16 (round-1 scatter store)
#pragma unroll
    for (int mt = 0; mt < 2; ++mt) {
#pragma unroll
      for (int r = 0; r < 4; ++r) {
        float x[4], sa = 0.f, sb = 0.f;
#pragma unroll
        for (int nt = 0; nt < 4; ++nt) {
          float xvv = leaky(acc[mt][nt][r] + b1v[nt]);
          x[nt] = xvv; sa += xvv; sb = fmaf(xvv, xvv, sb);
        }
#pragma unroll
        for (int off = 1; off < 16; off <<= 1) {
          sa += __shfl_xor(sa, off);
          sb += __shfl_xor(sb, off);
        }
        float mu = sa * (1.f / M1);
        float var = sb * (1.f / M1) - mu * mu;
        float inv = rsqrtf(var + EPS);
        int node = w * 32 + mt * 16 + lq * 4 + r;
#pragma unroll
        for (int nt = 0; nt < 4; ++nt)
          hb[node][nt * 16 + lr] = f2bf((x[nt] - mu) * inv * g1v[nt] + btv[nt]);
      }
    }
    __syncthreads();  // BAR-LN: hb visible (restored round-1 barrier)

    // ---- GEMM2: att logits [32 nodes x 8 heads], K=64
    f32x4 acc2[2];
    acc2[0] = (f32x4){0.f, 0.f, 0.f, 0.f};
    acc2[1] = (f32x4){0.f, 0.f, 0.f, 0.f};
#pragma unroll
    for (int c2 = 0; c2 < 2; ++c2) {
      short8 bfr2 = *(const short8*)&ovl.p.W2T[lr][c2 * 32 + lq * 8];
#pragma unroll
      for (int mt = 0; mt < 2; ++mt) {
        short8 af2 = *(const short8*)&hb[w * 32 + mt * 16 + lr][c2 * 32 + lq * 8];
        acc2[mt] = __builtin_amdgcn_mfma_f32_16x16x32_bf16(af2, bfr2, acc2[mt], 0, 0, 0);
      }
    }

    int gl_lo = gi[0];
    int gl_hi = gi[nvalid - 1];

    // ---- att = exp(.): attB[h][node] bf16; segment sums -> sL (LDS atomics)
    if (lr < NH) {
      float attv[2][4];
      int gnode[2][4];
#pragma unroll
      for (int mt = 0; mt < 2; ++mt)
#pragma unroll
        for (int r = 0; r < 4; ++r) {
          int node = w * 32 + mt * 16 + lq * 4 + r;
          float av = bf2f(f2bf(expf(acc2[mt][r] + b2v)));  // rounded value
          attv[mt][r] = av;
          gnode[mt][r] = gi[node];
          attB[lr][node] = f2bf(av);
        }
      for (int g = gl_lo; g <= gl_hi; ++g) {
        float ss = 0.f;
#pragma unroll
        for (int mt = 0; mt < 2; ++mt)
#pragma unroll
          for (int r = 0; r < 4; ++r)
            ss += (gnode[mt][r] == g) ? attv[mt][r] : 0.f;
        ss += __shfl_xor(ss, 16);
        ss += __shfl_xor(ss, 32);
        if (lq == 0) atomicAdd(&sL[g][lr], ss);
      }
    }
    __syncthreads();  // BAR2: attB ready

    // ---- aggregation MFMAs into register accs; skip kc spans with no nodes
    // of the target graph pair (gi sorted within chunk).
    int hA = lr & 7;
    int t0 = lr >> 3;       // graphs {0,1}
    int t1 = t0 + 2;        // graphs {2,3}
    __builtin_amdgcn_s_setprio(1);
#pragma unroll
    for (int kc = 0; kc < 4; ++kc) {
      int lo0 = gi[kc * 32];
      if (lo0 > 3) continue;               // whole span is tail
      int hi0 = gi[kc * 32 + 31];
      short8 av = *(const short8*)&attB[hA][kc * 32 + lq * 8];
      uchar8 gv = *(const uchar8*)&gi[kc * 32 + lq * 8];
      if (lo0 <= 1) {
        short8 a0;
#pragma unroll
        for (int j = 0; j < 8; ++j) a0[j] = (gv[j] == t0) ? av[j] : (short)0;
        c00 = __builtin_amdgcn_mfma_f32_16x16x32_bf16(a0, bfA[kc], c00, 0, 0, 0);
        c01 = __builtin_amdgcn_mfma_f32_16x16x32_bf16(a0, bfB[kc], c01, 0, 0, 0);
      }
      if (hi0 >= 2) {
        short8 a1;
#pragma unroll
        for (int j = 0; j < 8; ++j) a1[j] = (gv[j] == t1) ? av[j] : (short)0;
        c10 = __builtin_amdgcn_mfma_f32_16x16x32_bf16(a1, bfA[kc], c10, 0, 0, 0);
        c11 = __builtin_amdgcn_mfma_f32_16x16x32_bf16(a1, bfB[kc], c11, 0, 0, 0);
      }
    }
    __builtin_amdgcn_s_setprio(0);
  }
  __syncthreads();  // chunk work done (sL final; W1T/W2T & hb free)

  // ---- invert sL
  if (t < GPB * NH) {
    float sv = (&sL[0][0])[t];
    (&sL[0][0])[t] = sv > 0.f ? 1.f / sv : 0.f;
  }
  __syncthreads();

  // ---- normalized aggregates: registers -> aL[gi][h*128+d] bf16
  {
    int g0 = lq >> 1, g1i = g0 + 2;
    int hC = (lq & 1) * 4;
#pragma unroll
    for (int r = 0; r < 4; ++r) {
      float i0 = sL[g0][hC + r], i1 = sL[g1i][hC + r];
      aL[g0][(hC + r) * 128 + dA] = f2bf(c00[r] * i0);
      aL[g0][(hC + r) * 128 + dB] = f2bf(c01[r] * i0);
      aL[g1i][(hC + r) * 128 + dA] = f2bf(c10[r] * i1);
      aL[g1i][(hC + r) * 128 + dB] = f2bf(c11[r] * i1);
    }
  }
  __syncthreads();

  // ---- W3 GEMM: [4 graphs x 128], K=1024 (rows 4..15 duplicates, discarded)
  int ar = lr & 3;
  f32x4 acc3[2];
  acc3[0] = (f32x4){0.f, 0.f, 0.f, 0.f};
  acc3[1] = (f32x4){0.f, 0.f, 0.f, 0.f};
#pragma unroll
  for (int kc = 0; kc < 32; ++kc) {
    short8 a = *(const short8*)&aL[ar][kc * 32 + lq * 8];
#pragma unroll
    for (int nt = 0; nt < 2; ++nt) {
      int ncol = w * 32 + nt * 16 + lr;
      short8 b = *(const short8*)(W3T + (size_t)ncol * 1024 + kc * 32 + lq * 8);
      acc3[nt] = __builtin_amdgcn_mfma_f32_16x16x32_bf16(a, b, acc3[nt], 0, 0, 0);
    }
  }

  // ---- bias + leaky + LN(128) -> hbuf2 (4-wave reduction via red)
  float xv[2][4], sa[4] = {0.f, 0.f, 0.f, 0.f}, sb[4] = {0.f, 0.f, 0.f, 0.f};
#pragma unroll
  for (int nt = 0; nt < 2; ++nt) {
    float bb = b3[w * 32 + nt * 16 + lr];
#pragma unroll
    for (int r = 0; r < 4; ++r) {
      float v = leaky(acc3[nt][r] + bb);
      xv[nt][r] = v;
      sa[r] += v;
      sb[r] = fmaf(v, v, sb[r]);
    }
  }
#pragma unroll
  for (int off = 1; off < 16; off <<= 1)
#pragma unroll
    for (int r = 0; r < 4; ++r) {
      sa[r] += __shfl_xor(sa[r], off);
      sb[r] += __shfl_xor(sb[r], off);
    }
  if (lr == 0)
#pragma unroll
    for (int r = 0; r < 4; ++r) {
      ovl.e.red[w][0][lq * 4 + r] = sa[r];
      ovl.e.red[w][1][lq * 4 + r] = sb[r];
    }
  __syncthreads();
#pragma unroll
  for (int nt = 0; nt < 2; ++nt) {
    int col = w * 32 + nt * 16 + lr;
    float gg = g3[col], bt = beta3[col];
#pragma unroll
    for (int r = 0; r < 4; ++r) {
      int row = lq * 4 + r;
      float S1 = ovl.e.red[0][0][row] + ovl.e.red[1][0][row] +
                 ovl.e.red[2][0][row] + ovl.e.red[3][0][row];
      float S2 = ovl.e.red[0][1][row] + ovl.e.red[1][1][row] +
                 ovl.e.red[2][1][row] + ovl.e.red[3][1][row];
      float mu = S1 * (1.f / D);
      float var = S2 * (1.f / D) - mu * mu;
      float inv = rsqrtf(var + EPS);
      ovl.e.hbuf2[row][col] = f2bf((xv[nt][r] - mu) * inv * gg + bt);
    }
  }
  __syncthreads();

  // ---- W4 GEMM: [4 x 128], K=128
  f32x4 acc4[2];
  acc4[0] = (f32x4){0.f, 0.f, 0.f, 0.f};
  acc4[1] = (f32x4){0.f, 0.f, 0.f, 0.f};
#pragma unroll
  for (int kc = 0; kc < 4; ++kc) {
    short8 a2 = *(const short8*)&ovl.e.hbuf2[lr][kc * 32 + lq * 8];
#pragma unroll
    for (int nt = 0; nt < 2; ++nt) {
      int ncol = w * 32 + nt * 16 + lr;
      short8 b4f = *(const short8*)(W4T + (size_t)ncol * 128 + kc * 32 + lq * 8);
      acc4[nt] = __builtin_amdgcn_mfma_f32_16x16x32_bf16(a2, b4f, acc4[nt], 0, 0, 0);
    }
  }
#pragma unroll
  for (int r = 0; r < 4; ++r) { sa[r] = 0.f; sb[r] = 0.f; }
#pragma unroll
  for (int nt = 0; nt < 2; ++nt) {
    float bb = b4[w * 32 + nt * 16 + lr];
#pragma unroll
    for (int r = 0; r < 4; ++r) {
      float v = leaky(acc4[nt][r] + bb);
      xv[nt][r] = v;
      sa[r] += v;
      sb[r] = fmaf(v, v, sb[r]);
    }
  }
#pragma unroll
  for (int off = 1; off < 16; off <<= 1)
#pragma unroll
    for (int r = 0; r < 4; ++r) {
      sa[r] += __shfl_xor(sa[r], off);
      sb[r] += __shfl_xor(sb[r], off);
    }
  __syncthreads();
  if (lr == 0)
#pragma unroll
    for (int r = 0; r < 4; ++r) {
      ovl.e.red[w][0][lq * 4 + r] = sa[r];
      ovl.e.red[w][1][lq * 4 + r] = sb[r];
    }
  __syncthreads();
#pragma unroll
  for (int nt = 0; nt < 2; ++nt) {
    int col = w * 32 + nt * 16 + lr;
    float gg = g4[col], bt = beta4[col];
#pragma unroll
    for (int r = 0; r < 4; ++r) {
      int row = lq * 4 + r;
      if (row < GPB) {
        float S1 = ovl.e.red[0][0][row] + ovl.e.red[1][0][row] +
                   ovl.e.red[2][0][row] + ovl.e.red[3][0][row];
        float S2 = ovl.e.red[0][1][row] + ovl.e.red[1][1][row] +
                   ovl.e.red[2][1][row] + ovl.e.red[3][1][row];
        float mu = S1 * (1.f / D);
        float var = S2 * (1.f / D) - mu * mu;
        float inv = rsqrtf(var + EPS);
        out[(size_t)(G0 + row) * D + col] = (xv[nt][r] - mu) * inv * gg + bt;
      }
    }
  }
}

extern "C" void kernel_launch(void* const* d_in, const int* in_sizes, int n_in,
                              void* d_out, int out_size, void* d_ws, size_t ws_size,
                              hipStream_t stream) {
  (void)in_sizes; (void)n_in; (void)out_size; (void)ws_size;
  const float* feat  = (const float*)d_in[0];
  const int*   batch = (const int*)d_in[1];
  const float* W1    = (const float*)d_in[2];
  const float* b1    = (const float*)d_in[3];
  const float* g1    = (const float*)d_in[4];
  const float* beta1 = (const float*)d_in[5];
  const float* W2    = (const float*)d_in[6];
  const float* b2    = (const float*)d_in[7];
  const float* W3    = (const float*)d_in[8];
  const float* b3    = (const float*)d_in[9];
  const float* g3    = (const float*)d_in[10];
  const float* beta3 = (const float*)d_in[11];
  const float* W4    = (const float*)d_in[12];
  const float* b4    = (const float*)d_in[13];
  const float* g4    = (const float*)d_in[14];
  const float* beta4 = (const float*)d_in[15];
  float* out = (float*)d_out;

  char* ws = (char*)d_ws;
  short* W3T   = (short*)ws;                        // 256 KB
  short* W4T   = (short*)(ws + 262144);             // 32 KB
  int*  starts = (int*)(ws + 262144 + 32768);       // (NG+1)*4 B

  k0b_prep<<<52, 256, 0, stream>>>(W3, W4, batch, W3T, W4T, starts);
  k_fused<<<NG / GPB, 256, 0, stream>>>(feat, batch, starts, W1, b1, g1, beta1,
                                        W2, b2, W3T, b3, g3, beta3, W4T, b4, g4,
                                        beta4, out);
}

// Round 4
// 335.515 us; speedup vs baseline: 1.1482x; 1.1482x over previous
//
#include <hip/hip_runtime.h>
#include <math.h>

#define NG 4096
#define NN 262144
#define D 128
#define M1 64
#define NH 8
#define GPB 4          // graphs per block (contiguous node range, batch sorted)
#define EPS 1e-6f

typedef __attribute__((ext_vector_type(8))) short short8;
typedef __attribute__((ext_vector_type(8))) unsigned char uchar8;
typedef __attribute__((ext_vector_type(4))) float f32x4;

__device__ inline float leaky(float x) { return x > 0.f ? x : 0.01f * x; }

// fp32 -> bf16 round-to-nearest-even
__device__ inline short f2bf(float f) {
  union { float f; unsigned u; } v; v.f = f;
  unsigned r = (v.u + 0x7fffu + ((v.u >> 16) & 1u)) >> 16;
  return (short)r;
}
__device__ inline float bf2f(short s) {
  union { unsigned u; float f; } v;
  v.u = ((unsigned)(unsigned short)s) << 16;
  return v.f;
}

// ---------------------------------------------------------------------------
// Prep: blocks 0..35 transpose W3 -> W3T[128,1024] bf16, W4 -> W4T[128,128];
// blocks 36..51: starts[g] = lower_bound(batch, g); starts[NG] = NN.
// ---------------------------------------------------------------------------
__global__ __launch_bounds__(256) void k0b_prep(
    const float* __restrict__ W3, const float* __restrict__ W4,
    const int* __restrict__ batch,
    short* __restrict__ W3T, short* __restrict__ W4T,
    int* __restrict__ starts) {
  __shared__ float tile[64][65];
  int b = blockIdx.x, t = threadIdx.x;
  if (b >= 36) {
    int g = (b - 36) * 256 + t;
    int lo = 0, hi = NN;
    while (lo < hi) {
      int mid = (lo + hi) >> 1;
      if (batch[mid] < g) lo = mid + 1; else hi = mid;
    }
    starts[g] = lo;
    if (g == 0) starts[NG] = NN;
    return;
  }
  const float* src; short* dst; int kt, nt, tkl;
  if (b < 32) { src = W3; dst = W3T; kt = b >> 1; nt = b & 1; tkl = 1024; }
  else        { src = W4; dst = W4T; kt = (b - 32) >> 1; nt = (b - 32) & 1; tkl = 128; }

#pragma unroll
  for (int i = 0; i < 4; ++i) {
    int id = t + 256 * i;
    int r = id >> 4, c4 = (id & 15) * 4;
    float4 v = *(const float4*)(src + (size_t)(kt * 64 + r) * D + nt * 64 + c4);
    tile[r][c4 + 0] = v.x; tile[r][c4 + 1] = v.y;
    tile[r][c4 + 2] = v.z; tile[r][c4 + 3] = v.w;
  }
  __syncthreads();
  int n = t >> 2, kb = (t & 3) * 16;
  short8 p0, p1;
#pragma unroll
  for (int j = 0; j < 8; ++j) {
    p0[j] = f2bf(tile[kb + j][n]);
    p1[j] = f2bf(tile[kb + 8 + j][n]);
  }
  short* o = dst + (size_t)(nt * 64 + n) * tkl + kt * 64 + kb;
  *(short8*)o = p0;
  *(short8*)(o + 8) = p1;
}

// ---------------------------------------------------------------------------
// FUSED: one block owns graphs [G0, G0+4) = contiguous nodes [s0, s1).
// Aggregation accumulates in REGISTERS (fixed 4-graph window); 3 barriers per
// 128-node chunk; LDS 40.7 KB -> 4 blocks/CU.
// Round-4: spill fix — bfA/bfB loads moved back to post-BAR2 (round-1
// position) so afr+bf frags are never simultaneously live; peak VGPR < 128.
// ---------------------------------------------------------------------------
__global__ __launch_bounds__(256, 4) void k_fused(
    const float* __restrict__ feat, const int* __restrict__ batch,
    const int* __restrict__ starts,
    const float* __restrict__ W1, const float* __restrict__ b1,
    const float* __restrict__ g1, const float* __restrict__ beta1,
    const float* __restrict__ W2, const float* __restrict__ b2,
    const short* __restrict__ W3T, const float* __restrict__ b3,
    const float* __restrict__ g3, const float* __restrict__ beta3,
    const short* __restrict__ W4T, const float* __restrict__ b4,
    const float* __restrict__ g4, const float* __restrict__ beta4,
    float* __restrict__ out) {
  // prologue weights union epilogue buffers (disjoint in time)
  __shared__ __align__(16) union SOvl {
    struct { short W1T[M1][D + 8]; short W2T[16][M1 + 8]; } p;  // 19712 B
    struct { short hbuf2[16][136]; float red[4][2][16]; } e;    //  4864 B
  } ovl;
  __shared__ __align__(16) short hb[128][72];        // 18432 B; epilogue: aL
  __shared__ __align__(16) short attB[NH][136];      //  2176 B
  __shared__ float sL[GPB][NH];                      //   128 B
  __shared__ unsigned char giL2[2][128];             //   256 B   total 40704 B

  short (*aL)[1040] = (short(*)[1040])&hb[0][0];     // [gi][h*128+d] bf16

  int t = threadIdx.x;
  int G0 = blockIdx.x * GPB;
  int w = t >> 6, l = t & 63;
  int lr = l & 15, lq = l >> 4;
  int dA = w * 32 + lr, dB = dA + 16;

  // ---- one-time staging: W1T transposed bf16; W2T
#pragma unroll
  for (int i = 0; i < 8; ++i) {
    int idx4 = t + 256 * i;
    int k = idx4 >> 4, j = (idx4 & 15) * 4;
    float4 wv = *(const float4*)(W1 + k * M1 + j);
    ovl.p.W1T[j + 0][k] = f2bf(wv.x);
    ovl.p.W1T[j + 1][k] = f2bf(wv.y);
    ovl.p.W1T[j + 2][k] = f2bf(wv.z);
    ovl.p.W1T[j + 3][k] = f2bf(wv.w);
  }
#pragma unroll
  for (int i = 0; i < 4; ++i) {
    int e = t * 4 + i;
    int hh = e >> 6, j = e & 63;
    ovl.p.W2T[hh][j] = (hh < NH) ? f2bf(W2[j * NH + hh]) : (short)0;
  }
  if (t < GPB * NH) (&sL[0][0])[t] = 0.f;

  // per-lane constants hoisted
  float b1v[4], g1v[4], btv[4];
#pragma unroll
  for (int nt = 0; nt < 4; ++nt) {
    b1v[nt] = b1[nt * 16 + lr];
    g1v[nt] = g1[nt * 16 + lr];
    btv[nt] = beta1[nt * 16 + lr];
  }
  float b2v = b2[lr & 7];

  // register aggregation accumulators: fixed window covers graphs 0..3.
  // C row m=lq*4+r -> (gi = m>>3 (+2 for c1x), h = m&7); col -> d.
  f32x4 c00 = (f32x4){0.f, 0.f, 0.f, 0.f};
  f32x4 c01 = (f32x4){0.f, 0.f, 0.f, 0.f};
  f32x4 c10 = (f32x4){0.f, 0.f, 0.f, 0.f};
  f32x4 c11 = (f32x4){0.f, 0.f, 0.f, 0.f};

  int s0 = starts[G0], s1 = starts[G0 + GPB];
  int nchunks = (s1 - s0 + 127) >> 7;

  for (int c = 0; c < nchunks; ++c) {
    int base = s0 + (c << 7);
    int nvalid = min(128, s1 - base);
    unsigned char* gi = giL2[c & 1];
    if (t < 128)
      gi[t] = (t < nvalid) ? (unsigned char)(batch[base + t] - G0)
                           : (unsigned char)255;  // tail sentinel

    // ---- A-frags for GEMM1 (pre-barrier; latency overlaps other blocks)
    short8 afr[2][4];
#pragma unroll
    for (int mt = 0; mt < 2; ++mt) {
      int node = base + w * 32 + mt * 16 + lr;
      node = node < NN ? node : NN - 1;   // tail clamp (masked later)
      const float* rp = feat + (size_t)node * D + lq * 8;
#pragma unroll
      for (int cc = 0; cc < 4; ++cc) {
        float4 x0 = *(const float4*)(rp + cc * 32);
        float4 x1 = *(const float4*)(rp + cc * 32 + 4);
        short8 a;
        a[0] = f2bf(x0.x); a[1] = f2bf(x0.y); a[2] = f2bf(x0.z); a[3] = f2bf(x0.w);
        a[4] = f2bf(x1.x); a[5] = f2bf(x1.y); a[6] = f2bf(x1.z); a[7] = f2bf(x1.w);
        afr[mt][cc] = a;
      }
    }
    __syncthreads();  // BAR1: gi visible; prev chunk's attB/gi reads done

    // ---- GEMM1: [32 nodes x 64 j], K=128
    f32x4 acc[2][4];
#pragma unroll
    for (int mt = 0; mt < 2; ++mt)
#pragma unroll
      for (int nt = 0; nt < 4; ++nt) acc[mt][nt] = (f32x4){0.f, 0.f, 0.f, 0.f};
    __builtin_amdgcn_s_setprio(1);
#pragma unroll
    for (int cc = 0; cc < 4; ++cc) {
#pragma unroll
      for (int nt = 0; nt < 4; ++nt) {
        short8 bfr = *(const short8*)&ovl.p.W1T[nt * 16 + lr][cc * 32 + lq * 8];
        acc[0][nt] = __builtin_amdgcn_mfma_f32_16x16x32_bf16(afr[0][cc], bfr, acc[0][nt], 0, 0, 0);
        acc[1][nt] = __builtin_amdgcn_mfma_f32_16x16x32_bf16(afr[1][cc], bfr, acc[1][nt], 0, 0, 0);
      }
    }
    __builtin_amdgcn_s_setprio(0);

    // ---- bias + leaky + LN over j(64); h -> hb bf16
#pragma unroll
    for (int mt = 0; mt < 2; ++mt) {
#pragma unroll
      for (int r = 0; r < 4; ++r) {
        float x[4], sa = 0.f, sb = 0.f;
#pragma unroll
        for (int nt = 0; nt < 4; ++nt) {
          float xvv = leaky(acc[mt][nt][r] + b1v[nt]);
          x[nt] = xvv; sa += xvv; sb = fmaf(xvv, xvv, sb);
        }
#pragma unroll
        for (int off = 1; off < 16; off <<= 1) {
          sa += __shfl_xor(sa, off);
          sb += __shfl_xor(sb, off);
        }
        float mu = sa * (1.f / M1);
        float var = sb * (1.f / M1) - mu * mu;
        float inv = rsqrtf(var + EPS);
        int node = w * 32 + mt * 16 + lq * 4 + r;
#pragma unroll
        for (int nt = 0; nt < 4; ++nt)
          hb[node][nt * 16 + lr] = f2bf((x[nt] - mu) * inv * g1v[nt] + btv[nt]);
      }
    }
    __syncthreads();  // BAR-LN: hb visible

    // ---- GEMM2: att logits [32 nodes x 8 heads], K=64
    f32x4 acc2[2];
    acc2[0] = (f32x4){0.f, 0.f, 0.f, 0.f};
    acc2[1] = (f32x4){0.f, 0.f, 0.f, 0.f};
#pragma unroll
    for (int c2 = 0; c2 < 2; ++c2) {
      short8 bfr2 = *(const short8*)&ovl.p.W2T[lr][c2 * 32 + lq * 8];
#pragma unroll
      for (int mt = 0; mt < 2; ++mt) {
        short8 af2 = *(const short8*)&hb[w * 32 + mt * 16 + lr][c2 * 32 + lq * 8];
        acc2[mt] = __builtin_amdgcn_mfma_f32_16x16x32_bf16(af2, bfr2, acc2[mt], 0, 0, 0);
      }
    }

    int gl_lo = gi[0];
    int gl_hi = gi[nvalid - 1];

    // ---- att = exp(.): attB[h][node] bf16; segment sums -> sL (LDS atomics)
    if (lr < NH) {
      float attv[2][4];
      int gnode[2][4];
#pragma unroll
      for (int mt = 0; mt < 2; ++mt)
#pragma unroll
        for (int r = 0; r < 4; ++r) {
          int node = w * 32 + mt * 16 + lq * 4 + r;
          float av = bf2f(f2bf(expf(acc2[mt][r] + b2v)));  // rounded value
          attv[mt][r] = av;
          gnode[mt][r] = gi[node];
          attB[lr][node] = f2bf(av);
        }
      for (int g = gl_lo; g <= gl_hi; ++g) {
        float ss = 0.f;
#pragma unroll
        for (int mt = 0; mt < 2; ++mt)
#pragma unroll
          for (int r = 0; r < 4; ++r)
            ss += (gnode[mt][r] == g) ? attv[mt][r] : 0.f;
        ss += __shfl_xor(ss, 16);
        ss += __shfl_xor(ss, 32);
        if (lq == 0) atomicAdd(&sL[g][lr], ss);
      }
    }
    __syncthreads();  // BAR2: attB ready

    // ---- B-frags feat^T (L2-hot re-read of this chunk; post-BAR2 so they
    // are never live together with afr -> no spills)
    short8 bfA[4], bfB[4];
#pragma unroll
    for (int kc = 0; kc < 4; ++kc) {
      short8 ba, bb;
#pragma unroll
      for (int j = 0; j < 8; ++j) {
        int node = base + kc * 32 + lq * 8 + j;
        node = node < NN ? node : NN - 1;
        const float* fp = feat + (size_t)node * D;
        ba[j] = f2bf(fp[dA]);
        bb[j] = f2bf(fp[dB]);
      }
      bfA[kc] = ba;
      bfB[kc] = bb;
    }

    // ---- aggregation MFMAs into register accs; skip kc spans with no nodes
    // of the target graph pair (gi sorted within chunk).
    int hA = lr & 7;
    int t0 = lr >> 3;       // graphs {0,1}
    int t1 = t0 + 2;        // graphs {2,3}
    __builtin_amdgcn_s_setprio(1);
#pragma unroll
    for (int kc = 0; kc < 4; ++kc) {
      int lo0 = gi[kc * 32];
      if (lo0 > 3) continue;               // whole span is tail
      int hi0 = gi[kc * 32 + 31];
      short8 av = *(const short8*)&attB[hA][kc * 32 + lq * 8];
      uchar8 gv = *(const uchar8*)&gi[kc * 32 + lq * 8];
      if (lo0 <= 1) {
        short8 a0;
#pragma unroll
        for (int j = 0; j < 8; ++j) a0[j] = (gv[j] == t0) ? av[j] : (short)0;
        c00 = __builtin_amdgcn_mfma_f32_16x16x32_bf16(a0, bfA[kc], c00, 0, 0, 0);
        c01 = __builtin_amdgcn_mfma_f32_16x16x32_bf16(a0, bfB[kc], c01, 0, 0, 0);
      }
      if (hi0 >= 2) {
        short8 a1;
#pragma unroll
        for (int j = 0; j < 8; ++j) a1[j] = (gv[j] == t1) ? av[j] : (short)0;
        c10 = __builtin_amdgcn_mfma_f32_16x16x32_bf16(a1, bfA[kc], c10, 0, 0, 0);
        c11 = __builtin_amdgcn_mfma_f32_16x16x32_bf16(a1, bfB[kc], c11, 0, 0, 0);
      }
    }
    __builtin_amdgcn_s_setprio(0);
  }
  __syncthreads();  // chunk work done (sL final; W1T/W2T & hb free)

  // ---- invert sL
  if (t < GPB * NH) {
    float sv = (&sL[0][0])[t];
    (&sL[0][0])[t] = sv > 0.f ? 1.f / sv : 0.f;
  }
  __syncthreads();

  // ---- normalized aggregates: registers -> aL[gi][h*128+d] bf16
  {
    int g0 = lq >> 1, g1i = g0 + 2;
    int hC = (lq & 1) * 4;
#pragma unroll
    for (int r = 0; r < 4; ++r) {
      float i0 = sL[g0][hC + r], i1 = sL[g1i][hC + r];
      aL[g0][(hC + r) * 128 + dA] = f2bf(c00[r] * i0);
      aL[g0][(hC + r) * 128 + dB] = f2bf(c01[r] * i0);
      aL[g1i][(hC + r) * 128 + dA] = f2bf(c10[r] * i1);
      aL[g1i][(hC + r) * 128 + dB] = f2bf(c11[r] * i1);
    }
  }
  __syncthreads();

  // ---- W3 GEMM: [4 graphs x 128], K=1024 (rows 4..15 duplicates, discarded)
  int ar = lr & 3;
  f32x4 acc3[2];
  acc3[0] = (f32x4){0.f, 0.f, 0.f, 0.f};
  acc3[1] = (f32x4){0.f, 0.f, 0.f, 0.f};
#pragma unroll
  for (int kc = 0; kc < 32; ++kc) {
    short8 a = *(const short8*)&aL[ar][kc * 32 + lq * 8];
#pragma unroll
    for (int nt = 0; nt < 2; ++nt) {
      int ncol = w * 32 + nt * 16 + lr;
      short8 b = *(const short8*)(W3T + (size_t)ncol * 1024 + kc * 32 + lq * 8);
      acc3[nt] = __builtin_amdgcn_mfma_f32_16x16x32_bf16(a, b, acc3[nt], 0, 0, 0);
    }
  }

  // ---- bias + leaky + LN(128) -> hbuf2 (4-wave reduction via red)
  float xv[2][4], sa[4] = {0.f, 0.f, 0.f, 0.f}, sb[4] = {0.f, 0.f, 0.f, 0.f};
#pragma unroll
  for (int nt = 0; nt < 2; ++nt) {
    float bb = b3[w * 32 + nt * 16 + lr];
#pragma unroll
    for (int r = 0; r < 4; ++r) {
      float v = leaky(acc3[nt][r] + bb);
      xv[nt][r] = v;
      sa[r] += v;
      sb[r] = fmaf(v, v, sb[r]);
    }
  }
#pragma unroll
  for (int off = 1; off < 16; off <<= 1)
#pragma unroll
    for (int r = 0; r < 4; ++r) {
      sa[r] += __shfl_xor(sa[r], off);
      sb[r] += __shfl_xor(sb[r], off);
    }
  if (lr == 0)
#pragma unroll
    for (int r = 0; r < 4; ++r) {
      ovl.e.red[w][0][lq * 4 + r] = sa[r];
      ovl.e.red[w][1][lq * 4 + r] = sb[r];
    }
  __syncthreads();
#pragma unroll
  for (int nt = 0; nt < 2; ++nt) {
    int col = w * 32 + nt * 16 + lr;
    float gg = g3[col], bt = beta3[col];
#pragma unroll
    for (int r = 0; r < 4; ++r) {
      int row = lq * 4 + r;
      float S1 = ovl.e.red[0][0][row] + ovl.e.red[1][0][row] +
                 ovl.e.red[2][0][row] + ovl.e.red[3][0][row];
      float S2 = ovl.e.red[0][1][row] + ovl.e.red[1][1][row] +
                 ovl.e.red[2][1][row] + ovl.e.red[3][1][row];
      float mu = S1 * (1.f / D);
      float var = S2 * (1.f / D) - mu * mu;
      float inv = rsqrtf(var + EPS);
      ovl.e.hbuf2[row][col] = f2bf((xv[nt][r] - mu) * inv * gg + bt);
    }
  }
  __syncthreads();

  // ---- W4 GEMM: [4 x 128], K=128
  f32x4 acc4[2];
  acc4[0] = (f32x4){0.f, 0.f, 0.f, 0.f};
  acc4[1] = (f32x4){0.f, 0.f, 0.f, 0.f};
#pragma unroll
  for (int kc = 0; kc < 4; ++kc) {
    short8 a2 = *(const short8*)&ovl.e.hbuf2[lr][kc * 32 + lq * 8];
#pragma unroll
    for (int nt = 0; nt < 2; ++nt) {
      int ncol = w * 32 + nt * 16 + lr;
      short8 b4f = *(const short8*)(W4T + (size_t)ncol * 128 + kc * 32 + lq * 8);
      acc4[nt] = __builtin_amdgcn_mfma_f32_16x16x32_bf16(a2, b4f, acc4[nt], 0, 0, 0);
    }
  }
#pragma unroll
  for (int r = 0; r < 4; ++r) { sa[r] = 0.f; sb[r] = 0.f; }
#pragma unroll
  for (int nt = 0; nt < 2; ++nt) {
    float bb = b4[w * 32 + nt * 16 + lr];
#pragma unroll
    for (int r = 0; r < 4; ++r) {
      float v = leaky(acc4[nt][r] + bb);
      xv[nt][r] = v;
      sa[r] += v;
      sb[r] = fmaf(v, v, sb[r]);
    }
  }
#pragma unroll
  for (int off = 1; off < 16; off <<= 1)
#pragma unroll
    for (int r = 0; r < 4; ++r) {
      sa[r] += __shfl_xor(sa[r], off);
      sb[r] += __shfl_xor(sb[r], off);
    }
  __syncthreads();
  if (lr == 0)
#pragma unroll
    for (int r = 0; r < 4; ++r) {
      ovl.e.red[w][0][lq * 4 + r] = sa[r];
      ovl.e.red[w][1][lq * 4 + r] = sb[r];
    }
  __syncthreads();
#pragma unroll
  for (int nt = 0; nt < 2; ++nt) {
    int col = w * 32 + nt * 16 + lr;
    float gg = g4[col], bt = beta4[col];
#pragma unroll
    for (int r = 0; r < 4; ++r) {
      int row = lq * 4 + r;
      if (row < GPB) {
        float S1 = ovl.e.red[0][0][row] + ovl.e.red[1][0][row] +
                   ovl.e.red[2][0][row] + ovl.e.red[3][0][row];
        float S2 = ovl.e.red[0][1][row] + ovl.e.red[1][1][row] +
                   ovl.e.red[2][1][row] + ovl.e.red[3][1][row];
        float mu = S1 * (1.f / D);
        float var = S2 * (1.f / D) - mu * mu;
        float inv = rsqrtf(var + EPS);
        out[(size_t)(G0 + row) * D + col] = (xv[nt][r] - mu) * inv * gg + bt;
      }
    }
  }
}

extern "C" void kernel_launch(void* const* d_in, const int* in_sizes, int n_in,
                              void* d_out, int out_size, void* d_ws, size_t ws_size,
                              hipStream_t stream) {
  (void)in_sizes; (void)n_in; (void)out_size; (void)ws_size;
  const float* feat  = (const float*)d_in[0];
  const int*   batch = (const int*)d_in[1];
  const float* W1    = (const float*)d_in[2];
  const float* b1    = (const float*)d_in[3];
  const float* g1    = (const float*)d_in[4];
  const float* beta1 = (const float*)d_in[5];
  const float* W2    = (const float*)d_in[6];
  const float* b2    = (const float*)d_in[7];
  const float* W3    = (const float*)d_in[8];
  const float* b3    = (const float*)d_in[9];
  const float* g3    = (const float*)d_in[10];
  const float* beta3 = (const float*)d_in[11];
  const float* W4    = (const float*)d_in[12];
  const float* b4    = (const float*)d_in[13];
  const float* g4    = (const float*)d_in[14];
  const float* beta4 = (const float*)d_in[15];
  float* out = (float*)d_out;

  char* ws = (char*)d_ws;
  short* W3T   = (short*)ws;                        // 256 KB
  short* W4T   = (short*)(ws + 262144);             // 32 KB
  int*  starts = (int*)(ws + 262144 + 32768);       // (NG+1)*4 B

  k0b_prep<<<52, 256, 0, stream>>>(W3, W4, batch, W3T, W4T, starts);
  k_fused<<<NG / GPB, 256, 0, stream>>>(feat, batch, starts, W1, b1, g1, beta1,
                                        W2, b2, W3T, b3, g3, beta3, W4T, b4, g4,
                                        beta4, out);
}

// Round 5
// 290.079 us; speedup vs baseline: 1.3280x; 1.1566x over previous
//
#include <hip/hip_runtime.h>
#include <math.h>

#define NG 4096
#define NN 262144
#define D 128
#define M1 64
#define NH 8
#define GPB 4          // graphs per block (contiguous node range, batch sorted)
#define EPS 1e-6f

typedef __attribute__((ext_vector_type(8))) short short8;
typedef __attribute__((ext_vector_type(8))) unsigned char uchar8;
typedef __attribute__((ext_vector_type(4))) float f32x4;

__device__ inline float leaky(float x) { return x > 0.f ? x : 0.01f * x; }

// fp32 -> bf16 round-to-nearest-even
__device__ inline short f2bf(float f) {
  union { float f; unsigned u; } v; v.f = f;
  unsigned r = (v.u + 0x7fffu + ((v.u >> 16) & 1u)) >> 16;
  return (short)r;
}
__device__ inline float bf2f(short s) {
  union { unsigned u; float f; } v;
  v.u = ((unsigned)(unsigned short)s) << 16;
  return v.f;
}

// ---------------------------------------------------------------------------
// Prep: blocks 0..35 transpose W3 -> W3T[128,1024] bf16, W4 -> W4T[128,128];
// blocks 36..51: starts[g] = lower_bound(batch, g); starts[NG] = NN.
// ---------------------------------------------------------------------------
__global__ __launch_bounds__(256) void k0b_prep(
    const float* __restrict__ W3, const float* __restrict__ W4,
    const int* __restrict__ batch,
    short* __restrict__ W3T, short* __restrict__ W4T,
    int* __restrict__ starts) {
  __shared__ float tile[64][65];
  int b = blockIdx.x, t = threadIdx.x;
  if (b >= 36) {
    int g = (b - 36) * 256 + t;
    int lo = 0, hi = NN;
    while (lo < hi) {
      int mid = (lo + hi) >> 1;
      if (batch[mid] < g) lo = mid + 1; else hi = mid;
    }
    starts[g] = lo;
    if (g == 0) starts[NG] = NN;
    return;
  }
  const float* src; short* dst; int kt, nt, tkl;
  if (b < 32) { src = W3; dst = W3T; kt = b >> 1; nt = b & 1; tkl = 1024; }
  else        { src = W4; dst = W4T; kt = (b - 32) >> 1; nt = (b - 32) & 1; tkl = 128; }

#pragma unroll
  for (int i = 0; i < 4; ++i) {
    int id = t + 256 * i;
    int r = id >> 4, c4 = (id & 15) * 4;
    float4 v = *(const float4*)(src + (size_t)(kt * 64 + r) * D + nt * 64 + c4);
    tile[r][c4 + 0] = v.x; tile[r][c4 + 1] = v.y;
    tile[r][c4 + 2] = v.z; tile[r][c4 + 3] = v.w;
  }
  __syncthreads();
  int n = t >> 2, kb = (t & 3) * 16;
  short8 p0, p1;
#pragma unroll
  for (int j = 0; j < 8; ++j) {
    p0[j] = f2bf(tile[kb + j][n]);
    p1[j] = f2bf(tile[kb + 8 + j][n]);
  }
  short* o = dst + (size_t)(nt * 64 + n) * tkl + kt * 64 + kb;
  *(short8*)o = p0;
  *(short8*)(o + 8) = p1;
}

// ---------------------------------------------------------------------------
// FUSED: one block owns graphs [G0, G0+4) = contiguous nodes [s0, s1).
// Aggregation accumulates in REGISTERS (fixed 4-graph window); 3 barriers per
// 128-node chunk; LDS 40.7 KB.
// Round-5: __launch_bounds__(256,2) — the (256,4) combined VGPR cap of 128
// (unified arch+accum file) left ~64 arch regs and spilled ~200 MB/launch
// (rounds 3-4: WRITE_SIZE 234/104 MB vs 2 MB ideal). Cap 256 -> no spills,
// ~3 blocks/CU from LDS.
// ---------------------------------------------------------------------------
__global__ __launch_bounds__(256, 2) void k_fused(
    const float* __restrict__ feat, const int* __restrict__ batch,
    const int* __restrict__ starts,
    const float* __restrict__ W1, const float* __restrict__ b1,
    const float* __restrict__ g1, const float* __restrict__ beta1,
    const float* __restrict__ W2, const float* __restrict__ b2,
    const short* __restrict__ W3T, const float* __restrict__ b3,
    const float* __restrict__ g3, const float* __restrict__ beta3,
    const short* __restrict__ W4T, const float* __restrict__ b4,
    const float* __restrict__ g4, const float* __restrict__ beta4,
    float* __restrict__ out) {
  // prologue weights union epilogue buffers (disjoint in time)
  __shared__ __align__(16) union SOvl {
    struct { short W1T[M1][D + 8]; short W2T[16][M1 + 8]; } p;  // 19712 B
    struct { short hbuf2[16][136]; float red[4][2][16]; } e;    //  4864 B
  } ovl;
  __shared__ __align__(16) short hb[128][72];        // 18432 B; epilogue: aL
  __shared__ __align__(16) short attB[NH][136];      //  2176 B
  __shared__ float sL[GPB][NH];                      //   128 B
  __shared__ unsigned char giL2[2][128];             //   256 B   total 40704 B

  short (*aL)[1040] = (short(*)[1040])&hb[0][0];     // [gi][h*128+d] bf16

  int t = threadIdx.x;
  int G0 = blockIdx.x * GPB;
  int w = t >> 6, l = t & 63;
  int lr = l & 15, lq = l >> 4;
  int dA = w * 32 + lr, dB = dA + 16;

  // ---- one-time staging: W1T transposed bf16; W2T
#pragma unroll
  for (int i = 0; i < 8; ++i) {
    int idx4 = t + 256 * i;
    int k = idx4 >> 4, j = (idx4 & 15) * 4;
    float4 wv = *(const float4*)(W1 + k * M1 + j);
    ovl.p.W1T[j + 0][k] = f2bf(wv.x);
    ovl.p.W1T[j + 1][k] = f2bf(wv.y);
    ovl.p.W1T[j + 2][k] = f2bf(wv.z);
    ovl.p.W1T[j + 3][k] = f2bf(wv.w);
  }
#pragma unroll
  for (int i = 0; i < 4; ++i) {
    int e = t * 4 + i;
    int hh = e >> 6, j = e & 63;
    ovl.p.W2T[hh][j] = (hh < NH) ? f2bf(W2[j * NH + hh]) : (short)0;
  }
  if (t < GPB * NH) (&sL[0][0])[t] = 0.f;

  // per-lane constants hoisted
  float b1v[4], g1v[4], btv[4];
#pragma unroll
  for (int nt = 0; nt < 4; ++nt) {
    b1v[nt] = b1[nt * 16 + lr];
    g1v[nt] = g1[nt * 16 + lr];
    btv[nt] = beta1[nt * 16 + lr];
  }
  float b2v = b2[lr & 7];

  // register aggregation accumulators: fixed window covers graphs 0..3.
  // C row m=lq*4+r -> (gi = m>>3 (+2 for c1x), h = m&7); col -> d.
  f32x4 c00 = (f32x4){0.f, 0.f, 0.f, 0.f};
  f32x4 c01 = (f32x4){0.f, 0.f, 0.f, 0.f};
  f32x4 c10 = (f32x4){0.f, 0.f, 0.f, 0.f};
  f32x4 c11 = (f32x4){0.f, 0.f, 0.f, 0.f};

  int s0 = starts[G0], s1 = starts[G0 + GPB];
  int nchunks = (s1 - s0 + 127) >> 7;

  for (int c = 0; c < nchunks; ++c) {
    int base = s0 + (c << 7);
    int nvalid = min(128, s1 - base);
    unsigned char* gi = giL2[c & 1];
    if (t < 128)
      gi[t] = (t < nvalid) ? (unsigned char)(batch[base + t] - G0)
                           : (unsigned char)255;  // tail sentinel

    // ---- A-frags for GEMM1 (pre-barrier; latency overlaps other blocks)
    short8 afr[2][4];
#pragma unroll
    for (int mt = 0; mt < 2; ++mt) {
      int node = base + w * 32 + mt * 16 + lr;
      node = node < NN ? node : NN - 1;   // tail clamp (masked later)
      const float* rp = feat + (size_t)node * D + lq * 8;
#pragma unroll
      for (int cc = 0; cc < 4; ++cc) {
        float4 x0 = *(const float4*)(rp + cc * 32);
        float4 x1 = *(const float4*)(rp + cc * 32 + 4);
        short8 a;
        a[0] = f2bf(x0.x); a[1] = f2bf(x0.y); a[2] = f2bf(x0.z); a[3] = f2bf(x0.w);
        a[4] = f2bf(x1.x); a[5] = f2bf(x1.y); a[6] = f2bf(x1.z); a[7] = f2bf(x1.w);
        afr[mt][cc] = a;
      }
    }
    __syncthreads();  // BAR1: gi visible; prev chunk's attB/gi reads done

    // ---- GEMM1: [32 nodes x 64 j], K=128
    f32x4 acc[2][4];
#pragma unroll
    for (int mt = 0; mt < 2; ++mt)
#pragma unroll
      for (int nt = 0; nt < 4; ++nt) acc[mt][nt] = (f32x4){0.f, 0.f, 0.f, 0.f};
    __builtin_amdgcn_s_setprio(1);
#pragma unroll
    for (int cc = 0; cc < 4; ++cc) {
#pragma unroll
      for (int nt = 0; nt < 4; ++nt) {
        short8 bfr = *(const short8*)&ovl.p.W1T[nt * 16 + lr][cc * 32 + lq * 8];
        acc[0][nt] = __builtin_amdgcn_mfma_f32_16x16x32_bf16(afr[0][cc], bfr, acc[0][nt], 0, 0, 0);
        acc[1][nt] = __builtin_amdgcn_mfma_f32_16x16x32_bf16(afr[1][cc], bfr, acc[1][nt], 0, 0, 0);
      }
    }
    __builtin_amdgcn_s_setprio(0);

    // ---- bias + leaky + LN over j(64); h -> hb bf16
#pragma unroll
    for (int mt = 0; mt < 2; ++mt) {
#pragma unroll
      for (int r = 0; r < 4; ++r) {
        float x[4], sa = 0.f, sb = 0.f;
#pragma unroll
        for (int nt = 0; nt < 4; ++nt) {
          float xvv = leaky(acc[mt][nt][r] + b1v[nt]);
          x[nt] = xvv; sa += xvv; sb = fmaf(xvv, xvv, sb);
        }
#pragma unroll
        for (int off = 1; off < 16; off <<= 1) {
          sa += __shfl_xor(sa, off);
          sb += __shfl_xor(sb, off);
        }
        float mu = sa * (1.f / M1);
        float var = sb * (1.f / M1) - mu * mu;
        float inv = rsqrtf(var + EPS);
        int node = w * 32 + mt * 16 + lq * 4 + r;
#pragma unroll
        for (int nt = 0; nt < 4; ++nt)
          hb[node][nt * 16 + lr] = f2bf((x[nt] - mu) * inv * g1v[nt] + btv[nt]);
      }
    }
    __syncthreads();  // BAR-LN: hb visible

    // ---- GEMM2: att logits [32 nodes x 8 heads], K=64
    f32x4 acc2[2];
    acc2[0] = (f32x4){0.f, 0.f, 0.f, 0.f};
    acc2[1] = (f32x4){0.f, 0.f, 0.f, 0.f};
#pragma unroll
    for (int c2 = 0; c2 < 2; ++c2) {
      short8 bfr2 = *(const short8*)&ovl.p.W2T[lr][c2 * 32 + lq * 8];
#pragma unroll
      for (int mt = 0; mt < 2; ++mt) {
        short8 af2 = *(const short8*)&hb[w * 32 + mt * 16 + lr][c2 * 32 + lq * 8];
        acc2[mt] = __builtin_amdgcn_mfma_f32_16x16x32_bf16(af2, bfr2, acc2[mt], 0, 0, 0);
      }
    }

    int gl_lo = gi[0];
    int gl_hi = gi[nvalid - 1];

    // ---- att = exp(.): attB[h][node] bf16; segment sums -> sL (LDS atomics)
    if (lr < NH) {
      float attv[2][4];
      int gnode[2][4];
#pragma unroll
      for (int mt = 0; mt < 2; ++mt)
#pragma unroll
        for (int r = 0; r < 4; ++r) {
          int node = w * 32 + mt * 16 + lq * 4 + r;
          float av = bf2f(f2bf(expf(acc2[mt][r] + b2v)));  // rounded value
          attv[mt][r] = av;
          gnode[mt][r] = gi[node];
          attB[lr][node] = f2bf(av);
        }
      for (int g = gl_lo; g <= gl_hi; ++g) {
        float ss = 0.f;
#pragma unroll
        for (int mt = 0; mt < 2; ++mt)
#pragma unroll
          for (int r = 0; r < 4; ++r)
            ss += (gnode[mt][r] == g) ? attv[mt][r] : 0.f;
        ss += __shfl_xor(ss, 16);
        ss += __shfl_xor(ss, 32);
        if (lq == 0) atomicAdd(&sL[g][lr], ss);
      }
    }
    __syncthreads();  // BAR2: attB ready

    // ---- B-frags feat^T (L2-hot re-read of this chunk; post-BAR2 so they
    // are never live together with afr)
    short8 bfA[4], bfB[4];
#pragma unroll
    for (int kc = 0; kc < 4; ++kc) {
      short8 ba, bb;
#pragma unroll
      for (int j = 0; j < 8; ++j) {
        int node = base + kc * 32 + lq * 8 + j;
        node = node < NN ? node : NN - 1;
        const float* fp = feat + (size_t)node * D;
        ba[j] = f2bf(fp[dA]);
        bb[j] = f2bf(fp[dB]);
      }
      bfA[kc] = ba;
      bfB[kc] = bb;
    }

    // ---- aggregation MFMAs into register accs; skip kc spans with no nodes
    // of the target graph pair (gi sorted within chunk).
    int hA = lr & 7;
    int t0 = lr >> 3;       // graphs {0,1}
    int t1 = t0 + 2;        // graphs {2,3}
    __builtin_amdgcn_s_setprio(1);
#pragma unroll
    for (int kc = 0; kc < 4; ++kc) {
      int lo0 = gi[kc * 32];
      if (lo0 > 3) continue;               // whole span is tail
      int hi0 = gi[kc * 32 + 31];
      short8 av = *(const short8*)&attB[hA][kc * 32 + lq * 8];
      uchar8 gv = *(const uchar8*)&gi[kc * 32 + lq * 8];
      if (lo0 <= 1) {
        short8 a0;
#pragma unroll
        for (int j = 0; j < 8; ++j) a0[j] = (gv[j] == t0) ? av[j] : (short)0;
        c00 = __builtin_amdgcn_mfma_f32_16x16x32_bf16(a0, bfA[kc], c00, 0, 0, 0);
        c01 = __builtin_amdgcn_mfma_f32_16x16x32_bf16(a0, bfB[kc], c01, 0, 0, 0);
      }
      if (hi0 >= 2) {
        short8 a1;
#pragma unroll
        for (int j = 0; j < 8; ++j) a1[j] = (gv[j] == t1) ? av[j] : (short)0;
        c10 = __builtin_amdgcn_mfma_f32_16x16x32_bf16(a1, bfA[kc], c10, 0, 0, 0);
        c11 = __builtin_amdgcn_mfma_f32_16x16x32_bf16(a1, bfB[kc], c11, 0, 0, 0);
      }
    }
    __builtin_amdgcn_s_setprio(0);
  }
  __syncthreads();  // chunk work done (sL final; W1T/W2T & hb free)

  // ---- invert sL
  if (t < GPB * NH) {
    float sv = (&sL[0][0])[t];
    (&sL[0][0])[t] = sv > 0.f ? 1.f / sv : 0.f;
  }
  __syncthreads();

  // ---- normalized aggregates: registers -> aL[gi][h*128+d] bf16
  {
    int g0 = lq >> 1, g1i = g0 + 2;
    int hC = (lq & 1) * 4;
#pragma unroll
    for (int r = 0; r < 4; ++r) {
      float i0 = sL[g0][hC + r], i1 = sL[g1i][hC + r];
      aL[g0][(hC + r) * 128 + dA] = f2bf(c00[r] * i0);
      aL[g0][(hC + r) * 128 + dB] = f2bf(c01[r] * i0);
      aL[g1i][(hC + r) * 128 + dA] = f2bf(c10[r] * i1);
      aL[g1i][(hC + r) * 128 + dB] = f2bf(c11[r] * i1);
    }
  }
  __syncthreads();

  // ---- W3 GEMM: [4 graphs x 128], K=1024 (rows 4..15 duplicates, discarded)
  int ar = lr & 3;
  f32x4 acc3[2];
  acc3[0] = (f32x4){0.f, 0.f, 0.f, 0.f};
  acc3[1] = (f32x4){0.f, 0.f, 0.f, 0.f};
#pragma unroll
  for (int kc = 0; kc < 32; ++kc) {
    short8 a = *(const short8*)&aL[ar][kc * 32 + lq * 8];
#pragma unroll
    for (int nt = 0; nt < 2; ++nt) {
      int ncol = w * 32 + nt * 16 + lr;
      short8 b = *(const short8*)(W3T + (size_t)ncol * 1024 + kc * 32 + lq * 8);
      acc3[nt] = __builtin_amdgcn_mfma_f32_16x16x32_bf16(a, b, acc3[nt], 0, 0, 0);
    }
  }

  // ---- bias + leaky + LN(128) -> hbuf2 (4-wave reduction via red)
  float xv[2][4], sa[4] = {0.f, 0.f, 0.f, 0.f}, sb[4] = {0.f, 0.f, 0.f, 0.f};
#pragma unroll
  for (int nt = 0; nt < 2; ++nt) {
    float bb = b3[w * 32 + nt * 16 + lr];
#pragma unroll
    for (int r = 0; r < 4; ++r) {
      float v = leaky(acc3[nt][r] + bb);
      xv[nt][r] = v;
      sa[r] += v;
      sb[r] = fmaf(v, v, sb[r]);
    }
  }
#pragma unroll
  for (int off = 1; off < 16; off <<= 1)
#pragma unroll
    for (int r = 0; r < 4; ++r) {
      sa[r] += __shfl_xor(sa[r], off);
      sb[r] += __shfl_xor(sb[r], off);
    }
  if (lr == 0)
#pragma unroll
    for (int r = 0; r < 4; ++r) {
      ovl.e.red[w][0][lq * 4 + r] = sa[r];
      ovl.e.red[w][1][lq * 4 + r] = sb[r];
    }
  __syncthreads();
#pragma unroll
  for (int nt = 0; nt < 2; ++nt) {
    int col = w * 32 + nt * 16 + lr;
    float gg = g3[col], bt = beta3[col];
#pragma unroll
    for (int r = 0; r < 4; ++r) {
      int row = lq * 4 + r;
      float S1 = ovl.e.red[0][0][row] + ovl.e.red[1][0][row] +
                 ovl.e.red[2][0][row] + ovl.e.red[3][0][row];
      float S2 = ovl.e.red[0][1][row] + ovl.e.red[1][1][row] +
                 ovl.e.red[2][1][row] + ovl.e.red[3][1][row];
      float mu = S1 * (1.f / D);
      float var = S2 * (1.f / D) - mu * mu;
      float inv = rsqrtf(var + EPS);
      ovl.e.hbuf2[row][col] = f2bf((xv[nt][r] - mu) * inv * gg + bt);
    }
  }
  __syncthreads();

  // ---- W4 GEMM: [4 x 128], K=128
  f32x4 acc4[2];
  acc4[0] = (f32x4){0.f, 0.f, 0.f, 0.f};
  acc4[1] = (f32x4){0.f, 0.f, 0.f, 0.f};
#pragma unroll
  for (int kc = 0; kc < 4; ++kc) {
    short8 a2 = *(const short8*)&ovl.e.hbuf2[lr][kc * 32 + lq * 8];
#pragma unroll
    for (int nt = 0; nt < 2; ++nt) {
      int ncol = w * 32 + nt * 16 + lr;
      short8 b4f = *(const short8*)(W4T + (size_t)ncol * 128 + kc * 32 + lq * 8);
      acc4[nt] = __builtin_amdgcn_mfma_f32_16x16x32_bf16(a2, b4f, acc4[nt], 0, 0, 0);
    }
  }
#pragma unroll
  for (int r = 0; r < 4; ++r) { sa[r] = 0.f; sb[r] = 0.f; }
#pragma unroll
  for (int nt = 0; nt < 2; ++nt) {
    float bb = b4[w * 32 + nt * 16 + lr];
#pragma unroll
    for (int r = 0; r < 4; ++r) {
      float v = leaky(acc4[nt][r] + bb);
      xv[nt][r] = v;
      sa[r] += v;
      sb[r] = fmaf(v, v, sb[r]);
    }
  }
#pragma unroll
  for (int off = 1; off < 16; off <<= 1)
#pragma unroll
    for (int r = 0; r < 4; ++r) {
      sa[r] += __shfl_xor(sa[r], off);
      sb[r] += __shfl_xor(sb[r], off);
    }
  __syncthreads();
  if (lr == 0)
#pragma unroll
    for (int r = 0; r < 4; ++r) {
      ovl.e.red[w][0][lq * 4 + r] = sa[r];
      ovl.e.red[w][1][lq * 4 + r] = sb[r];
    }
  __syncthreads();
#pragma unroll
  for (int nt = 0; nt < 2; ++nt) {
    int col = w * 32 + nt * 16 + lr;
    float gg = g4[col], bt = beta4[col];
#pragma unroll
    for (int r = 0; r < 4; ++r) {
      int row = lq * 4 + r;
      if (row < GPB) {
        float S1 = ovl.e.red[0][0][row] + ovl.e.red[1][0][row] +
                   ovl.e.red[2][0][row] + ovl.e.red[3][0][row];
        float S2 = ovl.e.red[0][1][row] + ovl.e.red[1][1][row] +
                   ovl.e.red[2][1][row] + ovl.e.red[3][1][row];
        float mu = S1 * (1.f / D);
        float var = S2 * (1.f / D) - mu * mu;
        float inv = rsqrtf(var + EPS);
        out[(size_t)(G0 + row) * D + col] = (xv[nt][r] - mu) * inv * gg + bt;
      }
    }
  }
}

extern "C" void kernel_launch(void* const* d_in, const int* in_sizes, int n_in,
                              void* d_out, int out_size, void* d_ws, size_t ws_size,
                              hipStream_t stream) {
  (void)in_sizes; (void)n_in; (void)out_size; (void)ws_size;
  const float* feat  = (const float*)d_in[0];
  const int*   batch = (const int*)d_in[1];
  const float* W1    = (const float*)d_in[2];
  const float* b1    = (const float*)d_in[3];
  const float* g1    = (const float*)d_in[4];
  const float* beta1 = (const float*)d_in[5];
  const float* W2    = (const float*)d_in[6];
  const float* b2    = (const float*)d_in[7];
  const float* W3    = (const float*)d_in[8];
  const float* b3    = (const float*)d_in[9];
  const float* g3    = (const float*)d_in[10];
  const float* beta3 = (const float*)d_in[11];
  const float* W4    = (const float*)d_in[12];
  const float* b4    = (const float*)d_in[13];
  const float* g4    = (const float*)d_in[14];
  const float* beta4 = (const float*)d_in[15];
  float* out = (float*)d_out;

  char* ws = (char*)d_ws;
  short* W3T   = (short*)ws;                        // 256 KB
  short* W4T   = (short*)(ws + 262144);             // 32 KB
  int*  starts = (int*)(ws + 262144 + 32768);       // (NG+1)*4 B

  k0b_prep<<<52, 256, 0, stream>>>(W3, W4, batch, W3T, W4T, starts);
  k_fused<<<NG / GPB, 256, 0, stream>>>(feat, batch, starts, W1, b1, g1, beta1,
                                        W2, b2, W3T, b3, g3, beta3, W4T, b4, g4,
                                        beta4, out);
}

// Round 6
// 279.584 us; speedup vs baseline: 1.3779x; 1.0375x over previous
//
#include <hip/hip_runtime.h>
#include <math.h>

#define NG 4096
#define NN 262144
#define D 128
#define M1 64
#define NH 8
#define GPB 8          // graphs per block in kB (contiguous range, batch sorted)
#define EPS 1e-6f

typedef __attribute__((ext_vector_type(8))) short short8;
typedef __attribute__((ext_vector_type(4))) short short4v;
typedef __attribute__((ext_vector_type(4))) float f32x4;

__device__ inline float leaky(float x) { return x > 0.f ? x : 0.01f * x; }

// fp32 -> bf16 round-to-nearest-even
__device__ inline short f2bf(float f) {
  union { float f; unsigned u; } v; v.f = f;
  unsigned r = (v.u + 0x7fffu + ((v.u >> 16) & 1u)) >> 16;
  return (short)r;
}
__device__ inline float bf2f(short s) {
  union { unsigned u; float f; } v;
  v.u = ((unsigned)(unsigned short)s) << 16;
  return v.f;
}

// ---------------------------------------------------------------------------
// Prep: blocks 0..35 transpose W3 -> W3T[128,1024] bf16, W4 -> W4T[128,128];
// blocks 36..51: starts[g] = lower_bound(batch, g); starts[NG] = NN.
// ---------------------------------------------------------------------------
__global__ __launch_bounds__(256) void k0b_prep(
    const float* __restrict__ W3, const float* __restrict__ W4,
    const int* __restrict__ batch,
    short* __restrict__ W3T, short* __restrict__ W4T,
    int* __restrict__ starts) {
  __shared__ float tile[64][65];
  int b = blockIdx.x, t = threadIdx.x;
  if (b >= 36) {
    int g = (b - 36) * 256 + t;
    int lo = 0, hi = NN;
    while (lo < hi) {
      int mid = (lo + hi) >> 1;
      if (batch[mid] < g) lo = mid + 1; else hi = mid;
    }
    starts[g] = lo;
    if (g == 0) starts[NG] = NN;
    return;
  }
  const float* src; short* dst; int kt, nt, tkl;
  if (b < 32) { src = W3; dst = W3T; kt = b >> 1; nt = b & 1; tkl = 1024; }
  else        { src = W4; dst = W4T; kt = (b - 32) >> 1; nt = (b - 32) & 1; tkl = 128; }

#pragma unroll
  for (int i = 0; i < 4; ++i) {
    int id = t + 256 * i;
    int r = id >> 4, c4 = (id & 15) * 4;
    float4 v = *(const float4*)(src + (size_t)(kt * 64 + r) * D + nt * 64 + c4);
    tile[r][c4 + 0] = v.x; tile[r][c4 + 1] = v.y;
    tile[r][c4 + 2] = v.z; tile[r][c4 + 3] = v.w;
  }
  __syncthreads();
  int n = t >> 2, kb = (t & 3) * 16;
  short8 p0, p1;
#pragma unroll
  for (int j = 0; j < 8; ++j) {
    p0[j] = f2bf(tile[kb + j][n]);
    p1[j] = f2bf(tile[kb + 8 + j][n]);
  }
  short* o = dst + (size_t)(nt * 64 + n) * tkl + kt * 64 + kb;
  *(short8*)o = p0;
  *(short8*)(o + 8) = p1;
}

// ---------------------------------------------------------------------------
// kA: per 128-node tile (grid 2048, independent blocks, 4 blocks/CU):
// h = LN64(leaky(feat@W1+b1)); att = exp(h@W2+b2);
// attT[h][node] bf16 -> global (coalesced via LDS attB);
// s_sum[g][h] += partials (global atomics, round-0-proven register path).
// ---------------------------------------------------------------------------
__global__ __launch_bounds__(256, 2) void kA_att(
    const float* __restrict__ feat, const int* __restrict__ batch,
    const float* __restrict__ W1, const float* __restrict__ b1,
    const float* __restrict__ g1, const float* __restrict__ beta1,
    const float* __restrict__ W2, const float* __restrict__ b2,
    short* __restrict__ attT, float* __restrict__ s_sum) {
  __shared__ __align__(16) short W1T[M1][D + 8];   // 17408 B
  __shared__ __align__(16) short W2T[16][M1 + 8];  //  2304 B
  __shared__ __align__(16) short hb[128][72];      // 18432 B
  __shared__ __align__(16) short attB[NH][136];    //  2176 B
  __shared__ int batchL[128];                      //   512 B  total 40832 B

  int t = threadIdx.x;
  int nb = blockIdx.x * 128;
  int w = t >> 6, l = t & 63;
  int lr = l & 15, lq = l >> 4;

  // ---- stage W1T (transposed bf16), W2T, batchL
#pragma unroll
  for (int i = 0; i < 8; ++i) {
    int idx4 = t + 256 * i;
    int k = idx4 >> 4, j = (idx4 & 15) * 4;
    float4 wv = *(const float4*)(W1 + k * M1 + j);
    W1T[j + 0][k] = f2bf(wv.x);
    W1T[j + 1][k] = f2bf(wv.y);
    W1T[j + 2][k] = f2bf(wv.z);
    W1T[j + 3][k] = f2bf(wv.w);
  }
#pragma unroll
  for (int i = 0; i < 4; ++i) {
    int e = t * 4 + i;
    int hh = e >> 6, j = e & 63;
    W2T[hh][j] = (hh < NH) ? f2bf(W2[j * NH + hh]) : (short)0;
  }
  if (t < 128) batchL[t] = batch[nb + t];

  float b1v[4], g1v[4], btv[4];
#pragma unroll
  for (int nt = 0; nt < 4; ++nt) {
    b1v[nt] = b1[nt * 16 + lr];
    g1v[nt] = g1[nt * 16 + lr];
    btv[nt] = beta1[nt * 16 + lr];
  }
  float b2v = b2[lr & 7];

  // ---- A-frags (nb+127 < NN always; no clamp needed)
  short8 afr[2][4];
#pragma unroll
  for (int mt = 0; mt < 2; ++mt) {
    const float* rp = feat + (size_t)(nb + w * 32 + mt * 16 + lr) * D + lq * 8;
#pragma unroll
    for (int cc = 0; cc < 4; ++cc) {
      float4 x0 = *(const float4*)(rp + cc * 32);
      float4 x1 = *(const float4*)(rp + cc * 32 + 4);
      short8 a;
      a[0] = f2bf(x0.x); a[1] = f2bf(x0.y); a[2] = f2bf(x0.z); a[3] = f2bf(x0.w);
      a[4] = f2bf(x1.x); a[5] = f2bf(x1.y); a[6] = f2bf(x1.z); a[7] = f2bf(x1.w);
      afr[mt][cc] = a;
    }
  }
  __syncthreads();  // staging visible

  // ---- GEMM1: [32 nodes x 64 j], K=128
  f32x4 acc[2][4];
#pragma unroll
  for (int mt = 0; mt < 2; ++mt)
#pragma unroll
    for (int nt = 0; nt < 4; ++nt) acc[mt][nt] = (f32x4){0.f, 0.f, 0.f, 0.f};
  __builtin_amdgcn_s_setprio(1);
#pragma unroll
  for (int cc = 0; cc < 4; ++cc) {
#pragma unroll
    for (int nt = 0; nt < 4; ++nt) {
      short8 bfr = *(const short8*)&W1T[nt * 16 + lr][cc * 32 + lq * 8];
      acc[0][nt] = __builtin_amdgcn_mfma_f32_16x16x32_bf16(afr[0][cc], bfr, acc[0][nt], 0, 0, 0);
      acc[1][nt] = __builtin_amdgcn_mfma_f32_16x16x32_bf16(afr[1][cc], bfr, acc[1][nt], 0, 0, 0);
    }
  }
  __builtin_amdgcn_s_setprio(0);

  // ---- bias + leaky + LN over j(64); h -> hb bf16
#pragma unroll
  for (int mt = 0; mt < 2; ++mt) {
#pragma unroll
    for (int r = 0; r < 4; ++r) {
      float x[4], sa = 0.f, sb = 0.f;
#pragma unroll
      for (int nt = 0; nt < 4; ++nt) {
        float xvv = leaky(acc[mt][nt][r] + b1v[nt]);
        x[nt] = xvv; sa += xvv; sb = fmaf(xvv, xvv, sb);
      }
#pragma unroll
      for (int off = 1; off < 16; off <<= 1) {
        sa += __shfl_xor(sa, off);
        sb += __shfl_xor(sb, off);
      }
      float mu = sa * (1.f / M1);
      float var = sb * (1.f / M1) - mu * mu;
      float inv = rsqrtf(var + EPS);
      int node = w * 32 + mt * 16 + lq * 4 + r;
#pragma unroll
      for (int nt = 0; nt < 4; ++nt)
        hb[node][nt * 16 + lr] = f2bf((x[nt] - mu) * inv * g1v[nt] + btv[nt]);
    }
  }
  __syncthreads();  // hb visible

  // ---- GEMM2: att logits [32 nodes x 8 heads], K=64
  f32x4 acc2[2];
  acc2[0] = (f32x4){0.f, 0.f, 0.f, 0.f};
  acc2[1] = (f32x4){0.f, 0.f, 0.f, 0.f};
#pragma unroll
  for (int c2 = 0; c2 < 2; ++c2) {
    short8 bfr2 = *(const short8*)&W2T[lr][c2 * 32 + lq * 8];
#pragma unroll
    for (int mt = 0; mt < 2; ++mt) {
      short8 af2 = *(const short8*)&hb[w * 32 + mt * 16 + lr][c2 * 32 + lq * 8];
      acc2[mt] = __builtin_amdgcn_mfma_f32_16x16x32_bf16(af2, bfr2, acc2[mt], 0, 0, 0);
    }
  }

  int g_lo = batchL[0], g_hi = batchL[127];

  // ---- att = exp(.): attB[h][node] bf16; s partials -> global atomics
  if (lr < NH) {
    float attv[2][4];
    int bnode[2][4];
#pragma unroll
    for (int mt = 0; mt < 2; ++mt)
#pragma unroll
      for (int r = 0; r < 4; ++r) {
        int node = w * 32 + mt * 16 + lq * 4 + r;
        float av = bf2f(f2bf(expf(acc2[mt][r] + b2v)));  // rounded value
        attv[mt][r] = av;
        bnode[mt][r] = batchL[node];
        attB[lr][node] = f2bf(av);
      }
    for (int g = g_lo; g <= g_hi; ++g) {
      float ss = 0.f;
#pragma unroll
      for (int mt = 0; mt < 2; ++mt)
#pragma unroll
        for (int r = 0; r < 4; ++r)
          ss += (bnode[mt][r] == g) ? attv[mt][r] : 0.f;
      ss += __shfl_xor(ss, 16);
      ss += __shfl_xor(ss, 32);
      if (lq == 0) atomicAdd(s_sum + g * NH + lr, ss);
    }
  }
  __syncthreads();  // attB ready

  // ---- attT write: coalesced 8B per thread
  {
    int h = t >> 5, c4 = (t & 31) * 4;
    short4v v = *(const short4v*)&attB[h][c4];
    *(short4v*)(attT + (size_t)h * NN + nb + c4) = v;
  }
}

// ---------------------------------------------------------------------------
// kB: per 8-graph range (grid 512, all co-resident): masked aggregation GEMM
// (no barriers / no LDS in the chunk loop; batch values compared directly to
// global graph ids -> exact masks), then normalize + W3/LN/W4/LN epilogue.
// ---------------------------------------------------------------------------
__global__ __launch_bounds__(256, 2) void kB_agg(
    const float* __restrict__ feat, const int* __restrict__ batch,
    const int* __restrict__ starts, const short* __restrict__ attT,
    const float* __restrict__ s_sum,
    const short* __restrict__ W3T, const float* __restrict__ b3,
    const float* __restrict__ g3, const float* __restrict__ beta3,
    const short* __restrict__ W4T, const float* __restrict__ b4,
    const float* __restrict__ g4, const float* __restrict__ beta4,
    float* __restrict__ out) {
  __shared__ __align__(16) short aLb[GPB][1040];   // 16640 B
  __shared__ __align__(16) short hbuf2[16][136];   //  4352 B
  __shared__ float red[4][2][16];                  //   512 B
  __shared__ float sLb[GPB * NH];                  //   256 B  total ~21.8 KB

  int t = threadIdx.x;
  int G0 = blockIdx.x * GPB;
  int w = t >> 6, l = t & 63;
  int lr = l & 15, lq = l >> 4;
  int dA = w * 32 + lr, dB = dA + 16;
  int hA = lr & 7;
  int laneoff = lr >> 3;  // 0/1: which graph of the tile's pair this lane masks

  int s0 = starts[G0], s1 = starts[G0 + GPB];
  int base0 = s0 & ~127;                 // align chunks; prefix masked out
  int nch = (s1 - base0 + 127) >> 7;

  f32x4 cc[4][2];
#pragma unroll
  for (int T = 0; T < 4; ++T) {
    cc[T][0] = (f32x4){0.f, 0.f, 0.f, 0.f};
    cc[T][1] = (f32x4){0.f, 0.f, 0.f, 0.f};
  }

  for (int c = 0; c < nch; ++c) {
    int base = base0 + (c << 7);
    int lo0 = batch[base];
    int hi0 = batch[min(base + 127, NN - 1)];
    if (hi0 < G0 || lo0 > G0 + GPB - 1) continue;
    bool fastp = (base + 128 <= NN);
#pragma unroll 1
    for (int kc = 0; kc < 4; ++kc) {
      int nb0 = base + kc * 32;
      int klo = batch[min(nb0, NN - 1)];
      int khi = batch[min(nb0 + 31, NN - 1)];
      if (khi < G0 || klo > G0 + GPB - 1) continue;  // span outside window
      int n0 = nb0 + lq * 8;
      short8 av;
      int bv[8];
      short8 bfa, bfb;
      if (fastp) {
        av = *(const short8*)(attT + (size_t)hA * NN + n0);
        int4 bx = *(const int4*)(batch + n0);
        int4 by = *(const int4*)(batch + n0 + 4);
        bv[0] = bx.x; bv[1] = bx.y; bv[2] = bx.z; bv[3] = bx.w;
        bv[4] = by.x; bv[5] = by.y; bv[6] = by.z; bv[7] = by.w;
#pragma unroll
        for (int j = 0; j < 8; ++j) {
          const float* fp = feat + (size_t)(n0 + j) * D;
          bfa[j] = f2bf(fp[dA]);
          bfb[j] = f2bf(fp[dB]);
        }
      } else {  // rare tail: clamp; batch[NN-1]=4095 never matches (only the
                // last block reaches graph 4095 and it has no tail overshoot)
#pragma unroll
        for (int j = 0; j < 8; ++j) {
          int n = min(n0 + j, NN - 1);
          av[j] = attT[(size_t)hA * NN + n];
          bv[j] = batch[n];
          const float* fp = feat + (size_t)n * D;
          bfa[j] = f2bf(fp[dA]);
          bfb[j] = f2bf(fp[dB]);
        }
      }
#pragma unroll
      for (int T = 0; T < 4; ++T) {
        int tg = G0 + 2 * T;
        if (khi < tg || klo > tg + 1) continue;  // tile's 2 graphs absent
        int tgt = tg + laneoff;
        short8 am;
#pragma unroll
        for (int j = 0; j < 8; ++j) am[j] = (bv[j] == tgt) ? av[j] : (short)0;
        cc[T][0] = __builtin_amdgcn_mfma_f32_16x16x32_bf16(am, bfa, cc[T][0], 0, 0, 0);
        cc[T][1] = __builtin_amdgcn_mfma_f32_16x16x32_bf16(am, bfb, cc[T][1], 0, 0, 0);
      }
    }
  }

  // ---- inverse denominators
  if (t < GPB * NH) {
    float sv = s_sum[G0 * NH + t];
    sLb[t] = sv > 0.f ? 1.f / sv : 0.f;
  }
  __syncthreads();

  // ---- normalized aggregates -> aLb[gi][h*128+d] bf16
  // C row m=lq*4+r of tile T -> gi = 2T+(lq>>1), h = (lq&1)*4+r; col -> d.
#pragma unroll
  for (int T = 0; T < 4; ++T) {
    int gi = 2 * T + (lq >> 1);
    int hC = (lq & 1) * 4;
#pragma unroll
    for (int r = 0; r < 4; ++r) {
      float inv = sLb[gi * NH + hC + r];
      aLb[gi][(hC + r) * 128 + dA] = f2bf(cc[T][0][r] * inv);
      aLb[gi][(hC + r) * 128 + dB] = f2bf(cc[T][1][r] * inv);
    }
  }
  __syncthreads();

  // ---- W3 GEMM: [8 graphs x 128], K=1024 (rows 8..15 duplicates, discarded)
  int ar = lr & 7;
  f32x4 acc3[2];
  acc3[0] = (f32x4){0.f, 0.f, 0.f, 0.f};
  acc3[1] = (f32x4){0.f, 0.f, 0.f, 0.f};
#pragma unroll
  for (int kc = 0; kc < 32; ++kc) {
    short8 a = *(const short8*)&aLb[ar][kc * 32 + lq * 8];
#pragma unroll
    for (int nt = 0; nt < 2; ++nt) {
      int ncol = w * 32 + nt * 16 + lr;
      short8 b = *(const short8*)(W3T + (size_t)ncol * 1024 + kc * 32 + lq * 8);
      acc3[nt] = __builtin_amdgcn_mfma_f32_16x16x32_bf16(a, b, acc3[nt], 0, 0, 0);
    }
  }

  // ---- bias + leaky + LN(128) -> hbuf2 (4-wave reduction via red)
  float xv[2][4], sa[4] = {0.f, 0.f, 0.f, 0.f}, sb[4] = {0.f, 0.f, 0.f, 0.f};
#pragma unroll
  for (int nt = 0; nt < 2; ++nt) {
    float bb = b3[w * 32 + nt * 16 + lr];
#pragma unroll
    for (int r = 0; r < 4; ++r) {
      float v = leaky(acc3[nt][r] + bb);
      xv[nt][r] = v;
      sa[r] += v;
      sb[r] = fmaf(v, v, sb[r]);
    }
  }
#pragma unroll
  for (int off = 1; off < 16; off <<= 1)
#pragma unroll
    for (int r = 0; r < 4; ++r) {
      sa[r] += __shfl_xor(sa[r], off);
      sb[r] += __shfl_xor(sb[r], off);
    }
  if (lr == 0)
#pragma unroll
    for (int r = 0; r < 4; ++r) {
      red[w][0][lq * 4 + r] = sa[r];
      red[w][1][lq * 4 + r] = sb[r];
    }
  __syncthreads();
#pragma unroll
  for (int nt = 0; nt < 2; ++nt) {
    int col = w * 32 + nt * 16 + lr;
    float gg = g3[col], bt = beta3[col];
#pragma unroll
    for (int r = 0; r < 4; ++r) {
      int row = lq * 4 + r;
      float S1 = red[0][0][row] + red[1][0][row] + red[2][0][row] + red[3][0][row];
      float S2 = red[0][1][row] + red[1][1][row] + red[2][1][row] + red[3][1][row];
      float mu = S1 * (1.f / D);
      float var = S2 * (1.f / D) - mu * mu;
      float inv = rsqrtf(var + EPS);
      hbuf2[row][col] = f2bf((xv[nt][r] - mu) * inv * gg + bt);
    }
  }
  __syncthreads();

  // ---- W4 GEMM: [8 x 128], K=128
  f32x4 acc4[2];
  acc4[0] = (f32x4){0.f, 0.f, 0.f, 0.f};
  acc4[1] = (f32x4){0.f, 0.f, 0.f, 0.f};
#pragma unroll
  for (int kc = 0; kc < 4; ++kc) {
    short8 a2 = *(const short8*)&hbuf2[lr][kc * 32 + lq * 8];
#pragma unroll
    for (int nt = 0; nt < 2; ++nt) {
      int ncol = w * 32 + nt * 16 + lr;
      short8 b4f = *(const short8*)(W4T + (size_t)ncol * 128 + kc * 32 + lq * 8);
      acc4[nt] = __builtin_amdgcn_mfma_f32_16x16x32_bf16(a2, b4f, acc4[nt], 0, 0, 0);
    }
  }
#pragma unroll
  for (int r = 0; r < 4; ++r) { sa[r] = 0.f; sb[r] = 0.f; }
#pragma unroll
  for (int nt = 0; nt < 2; ++nt) {
    float bb = b4[w * 32 + nt * 16 + lr];
#pragma unroll
    for (int r = 0; r < 4; ++r) {
      float v = leaky(acc4[nt][r] + bb);
      xv[nt][r] = v;
      sa[r] += v;
      sb[r] = fmaf(v, v, sb[r]);
    }
  }
#pragma unroll
  for (int off = 1; off < 16; off <<= 1)
#pragma unroll
    for (int r = 0; r < 4; ++r) {
      sa[r] += __shfl_xor(sa[r], off);
      sb[r] += __shfl_xor(sb[r], off);
    }
  __syncthreads();
  if (lr == 0)
#pragma unroll
    for (int r = 0; r < 4; ++r) {
      red[w][0][lq * 4 + r] = sa[r];
      red[w][1][lq * 4 + r] = sb[r];
    }
  __syncthreads();
#pragma unroll
  for (int nt = 0; nt < 2; ++nt) {
    int col = w * 32 + nt * 16 + lr;
    float gg = g4[col], bt = beta4[col];
#pragma unroll
    for (int r = 0; r < 4; ++r) {
      int row = lq * 4 + r;
      if (row < GPB) {
        float S1 = red[0][0][row] + red[1][0][row] + red[2][0][row] + red[3][0][row];
        float S2 = red[0][1][row] + red[1][1][row] + red[2][1][row] + red[3][1][row];
        float mu = S1 * (1.f / D);
        float var = S2 * (1.f / D) - mu * mu;
        float inv = rsqrtf(var + EPS);
        out[(size_t)(G0 + row) * D + col] = (xv[nt][r] - mu) * inv * gg + bt;
      }
    }
  }
}

extern "C" void kernel_launch(void* const* d_in, const int* in_sizes, int n_in,
                              void* d_out, int out_size, void* d_ws, size_t ws_size,
                              hipStream_t stream) {
  (void)in_sizes; (void)n_in; (void)out_size; (void)ws_size;
  const float* feat  = (const float*)d_in[0];
  const int*   batch = (const int*)d_in[1];
  const float* W1    = (const float*)d_in[2];
  const float* b1    = (const float*)d_in[3];
  const float* g1    = (const float*)d_in[4];
  const float* beta1 = (const float*)d_in[5];
  const float* W2    = (const float*)d_in[6];
  const float* b2    = (const float*)d_in[7];
  const float* W3    = (const float*)d_in[8];
  const float* b3    = (const float*)d_in[9];
  const float* g3    = (const float*)d_in[10];
  const float* beta3 = (const float*)d_in[11];
  const float* W4    = (const float*)d_in[12];
  const float* b4    = (const float*)d_in[13];
  const float* g4    = (const float*)d_in[14];
  const float* beta4 = (const float*)d_in[15];
  float* out = (float*)d_out;

  char* ws = (char*)d_ws;
  short* W3T    = (short*)ws;                      // 262144 B
  short* W4T    = (short*)(ws + 262144);           //  32768 B
  int*   starts = (int*)(ws + 294912);             //  16388 B
  float* s_sum  = (float*)(ws + 311552);           // 131072 B
  short* attT   = (short*)(ws + 442624);           // 4 MB: [NH][NN] bf16

  hipMemsetAsync(s_sum, 0, (size_t)NG * NH * 4, stream);
  k0b_prep<<<52, 256, 0, stream>>>(W3, W4, batch, W3T, W4T, starts);
  kA_att<<<NN / 128, 256, 0, stream>>>(feat, batch, W1, b1, g1, beta1, W2, b2,
                                       attT, s_sum);
  kB_agg<<<NG / GPB, 256, 0, stream>>>(feat, batch, starts, attT, s_sum, W3T,
                                       b3, g3, beta3, W4T, b4, g4, beta4, out);
}